// Round 6
// baseline (581.058 us; speedup 1.0000x reference)
//
#include <hip/hip_runtime.h>
#include <math.h>

// Problem constants (fixed by setup_inputs)
static constexpr int Cc   = 16;   // C
static constexpr int COc  = 16;   // CO
static constexpr int Hh   = 4;    // heads
static constexpr int CHc  = 4;    // CO/H
static constexpr int CPWc = 32;   // 2*C
static constexpr int NTH  = 256;  // block size

// 16B loads only; immediately unpacked to scalar floats (round-1-proven
// codegen: no ext_vector locals -> no scratch demotion).
union F4 { float4 v; float f[4]; };

// ---------------------------------------------------------------------------
// Kernel 1: per-row first-layer projections (validated rounds 1-5).
// ---------------------------------------------------------------------------
__global__ __launch_bounds__(NTH) void ppa_precompute(
    const float* __restrict__ xq, const float* __restrict__ xk,
    const float* __restrict__ w1, const float* __restrict__ b1,
    const float* __restrict__ v1, const float* __restrict__ bv1,
    float* __restrict__ aW, float* __restrict__ aV,
    float* __restrict__ cW, float* __restrict__ cV,
    int BN, int BK) {
  __shared__ float sw1[CPWc * CPWc];  // 1024
  __shared__ float sv1[CPWc * COc];   // 512
  __shared__ float sb1[CPWc];
  __shared__ float sbv1[COc];
  const int t = threadIdx.x;
  for (int i = t; i < CPWc * CPWc; i += NTH) sw1[i] = w1[i];
  for (int i = t; i < CPWc * COc; i += NTH) sv1[i] = v1[i];
  if (t < CPWc) sb1[t] = b1[t];
  if (t < COc) sbv1[t] = bv1[t];
  __syncthreads();

  const int r = blockIdx.x * NTH + t;
  if (r >= BN + BK) return;
  const bool isQ = (r < BN);
  const int rr = isQ ? r : (r - BN);
  const float* src = isQ ? (xq + (size_t)rr * Cc) : (xk + (size_t)rr * Cc);

  float x[Cc];
#pragma unroll
  for (int i = 0; i < Cc; i += 4) {
    float4 v = *reinterpret_cast<const float4*>(src + i);
    x[i] = v.x; x[i + 1] = v.y; x[i + 2] = v.z; x[i + 3] = v.w;
  }

  if (isQ) {
#pragma unroll
    for (int j = 0; j < CPWc; ++j) {
      float acc = sb1[j];
#pragma unroll
      for (int i = 0; i < Cc; ++i)
        acc += x[i] * (sw1[i * CPWc + j] - sw1[(i + Cc) * CPWc + j]);
      aW[(size_t)rr * CPWc + j] = acc;
    }
#pragma unroll
    for (int j = 0; j < COc; ++j) {
      float acc = sbv1[j];
#pragma unroll
      for (int i = 0; i < Cc; ++i)
        acc += x[i] * (sv1[i * COc + j] - sv1[(i + Cc) * COc + j]);
      aV[(size_t)rr * COc + j] = acc;
    }
  } else {
#pragma unroll
    for (int j = 0; j < CPWc; ++j) {
      float acc = 0.f;
#pragma unroll
      for (int i = 0; i < Cc; ++i) acc += x[i] * sw1[(i + Cc) * CPWc + j];
      cW[(size_t)rr * CPWc + j] = acc;
    }
#pragma unroll
    for (int j = 0; j < COc; ++j) {
      float acc = 0.f;
#pragma unroll
      for (int i = 0; i < Cc; ++i) acc += x[i] * sv1[(i + Cc) * COc + j];
      cV[(size_t)rr * COc + j] = acc;
    }
  }
}

// ---------------------------------------------------------------------------
// Kernel 2: one block per (b,n) row; 256 threads; ONE k per thread per
// iteration (4 iterations, Nk=1024). Plain exp-sum softmax (logits ReLU'd
// >= 0; validated r1-r5). Uniforms (w2, v2 natural layout, a, av, bv2) in
// LDS, broadcast-read at point of use.
//
// REGISTER BUDGET (the r2-r5 lesson): with __launch_bounds__(256, w) the
// toolchain caps VGPRs at 256/w. arg=2 -> cap 128. The 2-k variant's live
// set (~150 with hoisted loads) spilled; this 1-k variant's live set is
// persistent 44 (lg4+p4+val16+o16+l4) + ~40 transient (3 in-flight float4
// global loads + LDS weight rows + addressing) ~= 90-110 < 128 -> no spill,
// 4 waves/SIMD.
// ---------------------------------------------------------------------------
__global__ __launch_bounds__(NTH, 2) void ppa_main(
    const float* __restrict__ aW, const float* __restrict__ aV,
    const float* __restrict__ cW, const float* __restrict__ cV,
    const float* __restrict__ w2, const float* __restrict__ b2,
    const float* __restrict__ v2, const float* __restrict__ bv2,
    float* __restrict__ out, int N, int Nk) {
  __shared__ __align__(16) float sw2[CPWc * Hh];   // [32][4] natural layout
  __shared__ __align__(16) float sv2[COc * COc];   // [16][16] natural layout
  __shared__ __align__(16) float sa[CPWc];
  __shared__ __align__(16) float sav[COc];
  __shared__ __align__(16) float sbv2[COc];
  __shared__ __align__(16) float sred[4][Hh + COc];

  const int t = threadIdx.x;
  const int row = blockIdx.x;  // [0, B*N)
  const int b = row / N;

  sv2[t] = v2[t];                       // NTH == 256 == 16*16
  if (t < CPWc * Hh) sw2[t] = w2[t];
  if (t < CPWc) sa[t] = aW[(size_t)row * CPWc + t];
  if (t < COc) { sav[t] = aV[(size_t)row * COc + t]; sbv2[t] = bv2[t]; }
  __syncthreads();

  // b2 is kernel-arg-uniform: compiler emits s_load -> SGPRs (4 values only).
  const float b20 = b2[0], b21 = b2[1], b22 = b2[2], b23 = b2[3];

  float l[Hh] = {0.f, 0.f, 0.f, 0.f};
  float o[COc];
#pragma unroll
  for (int c = 0; c < COc; ++c) o[c] = 0.f;

  const float* cWb = cW + (size_t)b * Nk * CPWc;
  const float* cVb = cV + (size_t)b * Nk * COc;

#pragma unroll 1
  for (int kk = 0; kk < Nk; kk += NTH) {
    const int k = kk + t;
    const float* pcw = cWb + (size_t)k * CPWc;
    const float* pcv = cVb + (size_t)k * COc;

    // ---- logits: lg = relu(a + cW_k) @ w2 + b2, streamed in 4-j blocks.
    float lg0 = b20, lg1 = b21, lg2 = b22, lg3 = b23;
#pragma unroll
    for (int q = 0; q < CPWc / 4; ++q) {
      F4 x4, a4;
      x4.v = *reinterpret_cast<const float4*>(pcw + 4 * q);
      a4.v = *reinterpret_cast<const float4*>(&sa[4 * q]);
#pragma unroll
      for (int jj = 0; jj < 4; ++jj) {
        const float hw = fmaxf(a4.f[jj] + x4.f[jj], 0.f);
        F4 w;
        w.v = *reinterpret_cast<const float4*>(&sw2[(4 * q + jj) * Hh]);
        lg0 += hw * w.f[0];
        lg1 += hw * w.f[1];
        lg2 += hw * w.f[2];
        lg3 += hw * w.f[3];
      }
    }
    float p[Hh];
    p[0] = __expf(fmaxf(lg0, 0.f));
    p[1] = __expf(fmaxf(lg1, 0.f));
    p[2] = __expf(fmaxf(lg2, 0.f));
    p[3] = __expf(fmaxf(lg3, 0.f));
    l[0] += p[0]; l[1] += p[1]; l[2] += p[2]; l[3] += p[3];

    // ---- values: val = relu(av + cV_k) @ v2 + bv2, streamed in 4-j blocks.
    float val[COc];
#pragma unroll
    for (int c4 = 0; c4 < COc; c4 += 4) {
      F4 bb;
      bb.v = *reinterpret_cast<const float4*>(&sbv2[c4]);
#pragma unroll
      for (int cc = 0; cc < 4; ++cc) val[c4 + cc] = bb.f[cc];
    }
#pragma unroll
    for (int q = 0; q < COc / 4; ++q) {
      F4 y4, av4;
      y4.v = *reinterpret_cast<const float4*>(pcv + 4 * q);
      av4.v = *reinterpret_cast<const float4*>(&sav[4 * q]);
#pragma unroll
      for (int jj = 0; jj < 4; ++jj) {
        const float hv = fmaxf(av4.f[jj] + y4.f[jj], 0.f);
        const int j = 4 * q + jj;
#pragma unroll
        for (int c4 = 0; c4 < COc; c4 += 4) {
          F4 w;
          w.v = *reinterpret_cast<const float4*>(&sv2[j * COc + c4]);
#pragma unroll
          for (int cc = 0; cc < 4; ++cc) val[c4 + cc] += hv * w.f[cc];
        }
      }
    }
#pragma unroll
    for (int c = 0; c < COc; ++c) o[c] += p[c >> 2] * fmaxf(val[c], 0.f);
  }

  // ---- plain-sum reduction: wave butterfly, then cross-wave via LDS.
#pragma unroll
  for (int off = 1; off < 64; off <<= 1) {
#pragma unroll
    for (int h = 0; h < Hh; ++h) l[h] += __shfl_xor(l[h], off);
#pragma unroll
    for (int c = 0; c < COc; ++c) o[c] += __shfl_xor(o[c], off);
  }
  const int lane = t & 63;
  const int wid = t >> 6;
  if (lane == 0) {
#pragma unroll
    for (int h = 0; h < Hh; ++h) sred[wid][h] = l[h];
#pragma unroll
    for (int c = 0; c < COc; ++c) sred[wid][Hh + c] = o[c];
  }
  __syncthreads();

  if (t < COc) {
    const int h = t >> 2;
    float lsum = 0.f, osum = 0.f;
#pragma unroll
    for (int w = 0; w < 4; ++w) {
      lsum += sred[w][h];
      osum += sred[w][Hh + t];
    }
    out[(size_t)row * COc + t] = osum / lsum;
  }
}

// ---------------------------------------------------------------------------
extern "C" void kernel_launch(void* const* d_in, const int* in_sizes, int n_in,
                              void* d_out, int out_size, void* d_ws, size_t ws_size,
                              hipStream_t stream) {
  const float* xq  = (const float*)d_in[0];
  const float* xk  = (const float*)d_in[1];
  const float* w1  = (const float*)d_in[2];
  const float* b1  = (const float*)d_in[3];
  const float* w2  = (const float*)d_in[4];
  const float* b2  = (const float*)d_in[5];
  const float* v1  = (const float*)d_in[6];
  const float* bv1 = (const float*)d_in[7];
  const float* v2  = (const float*)d_in[8];
  const float* bv2 = (const float*)d_in[9];
  float* out = (float*)d_out;

  const int BN = in_sizes[0] / Cc;  // B*N  = 2048
  const int BK = in_sizes[1] / Cc;  // B*Nk = 2048
  const int B = 2;                  // fixed by setup_inputs
  const int N = BN / B;
  const int Nk = BK / B;

  float* ws = (float*)d_ws;
  float* aW = ws;                          // BN*32
  float* aV = aW + (size_t)BN * CPWc;      // BN*16
  float* cW = aV + (size_t)BN * COc;       // BK*32
  float* cV = cW + (size_t)BK * CPWc;      // BK*16

  const int totalRows = BN + BK;
  const int pgrid = (totalRows + NTH - 1) / NTH;
  ppa_precompute<<<pgrid, NTH, 0, stream>>>(xq, xk, w1, b1, v1, bv1,
                                            aW, aV, cW, cV, BN, BK);
  ppa_main<<<BN, NTH, 0, stream>>>(aW, aV, cW, cV, w2, b2, v2, bv2, out, N, Nk);
}

// Round 7
// 117.668 us; speedup vs baseline: 4.9381x; 4.9381x over previous
//
#include <hip/hip_runtime.h>
#include <math.h>

// Problem constants (fixed by setup_inputs)
static constexpr int Cc   = 16;   // C
static constexpr int COc  = 16;   // CO
static constexpr int Hh   = 4;    // heads
static constexpr int CHc  = 4;    // CO/H
static constexpr int CPWc = 32;   // 2*C
static constexpr int NTH  = 256;  // block size

// 16B loads only; immediately unpacked to scalar floats (round-1-proven
// codegen: no ext_vector locals -> no scratch demotion).
union F4 { float4 v; float f[4]; };

// ---------------------------------------------------------------------------
// Kernel 1: per-row first-layer projections (validated rounds 1-6).
// ---------------------------------------------------------------------------
__global__ __launch_bounds__(NTH) void ppa_precompute(
    const float* __restrict__ xq, const float* __restrict__ xk,
    const float* __restrict__ w1, const float* __restrict__ b1,
    const float* __restrict__ v1, const float* __restrict__ bv1,
    float* __restrict__ aW, float* __restrict__ aV,
    float* __restrict__ cW, float* __restrict__ cV,
    int BN, int BK) {
  __shared__ float sw1[CPWc * CPWc];  // 1024
  __shared__ float sv1[CPWc * COc];   // 512
  __shared__ float sb1[CPWc];
  __shared__ float sbv1[COc];
  const int t = threadIdx.x;
  for (int i = t; i < CPWc * CPWc; i += NTH) sw1[i] = w1[i];
  for (int i = t; i < CPWc * COc; i += NTH) sv1[i] = v1[i];
  if (t < CPWc) sb1[t] = b1[t];
  if (t < COc) sbv1[t] = bv1[t];
  __syncthreads();

  const int r = blockIdx.x * NTH + t;
  if (r >= BN + BK) return;
  const bool isQ = (r < BN);
  const int rr = isQ ? r : (r - BN);
  const float* src = isQ ? (xq + (size_t)rr * Cc) : (xk + (size_t)rr * Cc);

  float x[Cc];
#pragma unroll
  for (int i = 0; i < Cc; i += 4) {
    float4 v = *reinterpret_cast<const float4*>(src + i);
    x[i] = v.x; x[i + 1] = v.y; x[i + 2] = v.z; x[i + 3] = v.w;
  }

  if (isQ) {
#pragma unroll
    for (int j = 0; j < CPWc; ++j) {
      float acc = sb1[j];
#pragma unroll
      for (int i = 0; i < Cc; ++i)
        acc += x[i] * (sw1[i * CPWc + j] - sw1[(i + Cc) * CPWc + j]);
      aW[(size_t)rr * CPWc + j] = acc;
    }
#pragma unroll
    for (int j = 0; j < COc; ++j) {
      float acc = sbv1[j];
#pragma unroll
      for (int i = 0; i < Cc; ++i)
        acc += x[i] * (sv1[i * COc + j] - sv1[(i + Cc) * COc + j]);
      aV[(size_t)rr * COc + j] = acc;
    }
  } else {
#pragma unroll
    for (int j = 0; j < CPWc; ++j) {
      float acc = 0.f;
#pragma unroll
      for (int i = 0; i < Cc; ++i) acc += x[i] * sw1[(i + Cc) * CPWc + j];
      cW[(size_t)rr * CPWc + j] = acc;
    }
#pragma unroll
    for (int j = 0; j < COc; ++j) {
      float acc = 0.f;
#pragma unroll
      for (int i = 0; i < Cc; ++i) acc += x[i] * sv1[(i + Cc) * COc + j];
      cV[(size_t)rr * COc + j] = acc;
    }
  }
}

// ---------------------------------------------------------------------------
// Kernel 2: one block per (b,n) row; 256 threads; ONE k per thread per
// iteration (4 iterations, Nk=1024). Plain exp-sum softmax (logits ReLU'd
// >= 0; validated r1-r6). Uniforms (w2, v2 natural layout, a, av, bv2) in
// LDS; every in-loop LDS read is wave-uniform -> broadcast, conflict-free.
//
// REGISTER LAW (measured r1-r6): __launch_bounds__(256, w) caps VGPR at
// 256/w and ANY cap triggered scratch spill of the accumulator arrays
// (FETCH/WRITE in the 0.5-1.6 GB range, VALUBusy < 10%). The only never-
// spilled configuration is an UNCAPPED allocation (r1: VGPR 256, FETCH
// 4 MB). So: no min-waves argument. Correctness of codegen > occupancy.
// ---------------------------------------------------------------------------
__global__ __launch_bounds__(NTH) void ppa_main(
    const float* __restrict__ aW, const float* __restrict__ aV,
    const float* __restrict__ cW, const float* __restrict__ cV,
    const float* __restrict__ w2, const float* __restrict__ b2,
    const float* __restrict__ v2, const float* __restrict__ bv2,
    float* __restrict__ out, int N, int Nk) {
  __shared__ __align__(16) float sw2[CPWc * Hh];   // [32][4] natural layout
  __shared__ __align__(16) float sv2[COc * COc];   // [16][16] natural layout
  __shared__ __align__(16) float sa[CPWc];
  __shared__ __align__(16) float sav[COc];
  __shared__ __align__(16) float sbv2[COc];
  __shared__ __align__(16) float sred[4][Hh + COc];

  const int t = threadIdx.x;
  const int row = blockIdx.x;  // [0, B*N)
  const int b = row / N;

  sv2[t] = v2[t];                       // NTH == 256 == 16*16
  if (t < CPWc * Hh) sw2[t] = w2[t];
  if (t < CPWc) sa[t] = aW[(size_t)row * CPWc + t];
  if (t < COc) { sav[t] = aV[(size_t)row * COc + t]; sbv2[t] = bv2[t]; }
  __syncthreads();

  // b2 is kernel-arg-uniform: compiler emits s_load -> SGPRs (4 values only).
  const float b20 = b2[0], b21 = b2[1], b22 = b2[2], b23 = b2[3];

  float l[Hh] = {0.f, 0.f, 0.f, 0.f};
  float o[COc];
#pragma unroll
  for (int c = 0; c < COc; ++c) o[c] = 0.f;

  // Marching pointers: one add per iteration instead of 64-bit k*stride.
  const float* pcw = cW + (size_t)b * Nk * CPWc + (size_t)t * CPWc;
  const float* pcv = cV + (size_t)b * Nk * COc + (size_t)t * COc;

#pragma unroll 1
  for (int it = 0; it < Nk / NTH; ++it) {
    // ---- logits: lg = relu(a + cW_k) @ w2 + b2, streamed in 4-j blocks.
    float lg0 = b20, lg1 = b21, lg2 = b22, lg3 = b23;
#pragma unroll
    for (int q = 0; q < CPWc / 4; ++q) {
      F4 x4, a4;
      x4.v = *reinterpret_cast<const float4*>(pcw + 4 * q);
      a4.v = *reinterpret_cast<const float4*>(&sa[4 * q]);
#pragma unroll
      for (int jj = 0; jj < 4; ++jj) {
        const float hw = fmaxf(a4.f[jj] + x4.f[jj], 0.f);
        F4 w;
        w.v = *reinterpret_cast<const float4*>(&sw2[(4 * q + jj) * Hh]);
        lg0 += hw * w.f[0];
        lg1 += hw * w.f[1];
        lg2 += hw * w.f[2];
        lg3 += hw * w.f[3];
      }
    }
    float p[Hh];
    p[0] = __expf(fmaxf(lg0, 0.f));
    p[1] = __expf(fmaxf(lg1, 0.f));
    p[2] = __expf(fmaxf(lg2, 0.f));
    p[3] = __expf(fmaxf(lg3, 0.f));
    l[0] += p[0]; l[1] += p[1]; l[2] += p[2]; l[3] += p[3];

    // ---- values: val = relu(av + cV_k) @ v2 + bv2, streamed in 4-j blocks.
    float val[COc];
#pragma unroll
    for (int c4 = 0; c4 < COc; c4 += 4) {
      F4 bb;
      bb.v = *reinterpret_cast<const float4*>(&sbv2[c4]);
#pragma unroll
      for (int cc = 0; cc < 4; ++cc) val[c4 + cc] = bb.f[cc];
    }
#pragma unroll
    for (int q = 0; q < COc / 4; ++q) {
      F4 y4, av4;
      y4.v = *reinterpret_cast<const float4*>(pcv + 4 * q);
      av4.v = *reinterpret_cast<const float4*>(&sav[4 * q]);
#pragma unroll
      for (int jj = 0; jj < 4; ++jj) {
        const float hv = fmaxf(av4.f[jj] + y4.f[jj], 0.f);
        const int j = 4 * q + jj;
#pragma unroll
        for (int c4 = 0; c4 < COc; c4 += 4) {
          F4 w;
          w.v = *reinterpret_cast<const float4*>(&sv2[j * COc + c4]);
#pragma unroll
          for (int cc = 0; cc < 4; ++cc) val[c4 + cc] += hv * w.f[cc];
        }
      }
    }
#pragma unroll
    for (int c = 0; c < COc; ++c) o[c] += p[c >> 2] * fmaxf(val[c], 0.f);

    pcw += (size_t)NTH * CPWc;
    pcv += (size_t)NTH * COc;
  }

  // ---- plain-sum reduction: wave butterfly, then cross-wave via LDS.
#pragma unroll
  for (int off = 1; off < 64; off <<= 1) {
#pragma unroll
    for (int h = 0; h < Hh; ++h) l[h] += __shfl_xor(l[h], off);
#pragma unroll
    for (int c = 0; c < COc; ++c) o[c] += __shfl_xor(o[c], off);
  }
  const int lane = t & 63;
  const int wid = t >> 6;
  if (lane == 0) {
#pragma unroll
    for (int h = 0; h < Hh; ++h) sred[wid][h] = l[h];
#pragma unroll
    for (int c = 0; c < COc; ++c) sred[wid][Hh + c] = o[c];
  }
  __syncthreads();

  if (t < COc) {
    const int h = t >> 2;
    float lsum = 0.f, osum = 0.f;
#pragma unroll
    for (int w = 0; w < 4; ++w) {
      lsum += sred[w][h];
      osum += sred[w][Hh + t];
    }
    out[(size_t)row * COc + t] = osum / lsum;
  }
}

// ---------------------------------------------------------------------------
extern "C" void kernel_launch(void* const* d_in, const int* in_sizes, int n_in,
                              void* d_out, int out_size, void* d_ws, size_t ws_size,
                              hipStream_t stream) {
  const float* xq  = (const float*)d_in[0];
  const float* xk  = (const float*)d_in[1];
  const float* w1  = (const float*)d_in[2];
  const float* b1  = (const float*)d_in[3];
  const float* w2  = (const float*)d_in[4];
  const float* b2  = (const float*)d_in[5];
  const float* v1  = (const float*)d_in[6];
  const float* bv1 = (const float*)d_in[7];
  const float* v2  = (const float*)d_in[8];
  const float* bv2 = (const float*)d_in[9];
  float* out = (float*)d_out;

  const int BN = in_sizes[0] / Cc;  // B*N  = 2048
  const int BK = in_sizes[1] / Cc;  // B*Nk = 2048
  const int B = 2;                  // fixed by setup_inputs
  const int N = BN / B;
  const int Nk = BK / B;

  float* ws = (float*)d_ws;
  float* aW = ws;                          // BN*32
  float* aV = aW + (size_t)BN * CPWc;      // BN*16
  float* cW = aV + (size_t)BN * COc;       // BK*32
  float* cV = cW + (size_t)BK * CPWc;      // BK*16

  const int totalRows = BN + BK;
  const int pgrid = (totalRows + NTH - 1) / NTH;
  ppa_precompute<<<pgrid, NTH, 0, stream>>>(xq, xk, w1, b1, v1, bv1,
                                            aW, aV, cW, cV, BN, BK);
  ppa_main<<<BN, NTH, 0, stream>>>(aW, aV, cW, cV, w2, b2, v2, bv2, out, N, Nk);
}

// Round 8
// 58.069 us; speedup vs baseline: 10.0063x; 2.0263x over previous
//
#include <hip/hip_runtime.h>
#include <hip/hip_bf16.h>
#include <math.h>

// Problem constants (fixed by setup_inputs)
static constexpr int Cc   = 16;   // C
static constexpr int COc  = 16;   // CO
static constexpr int Hh   = 4;    // heads
static constexpr int CPWc = 32;   // 2*C
static constexpr int NTH  = 256;  // block size

typedef __attribute__((ext_vector_type(8))) short bf16x8;   // 8 bf16 = 4 VGPR
typedef __attribute__((ext_vector_type(4))) float f32x4v;   // MFMA C/D

union F4 { float4 v; float f[4]; };

__device__ __forceinline__ short f2bf(float x) {
  __hip_bfloat16 h = __float2bfloat16(x);
  return *reinterpret_cast<short*>(&h);
}

// ---------------------------------------------------------------------------
// Kernel 1: per-row first-layer projections (validated rounds 1-7, fp32).
// ---------------------------------------------------------------------------
__global__ __launch_bounds__(NTH) void ppa_precompute(
    const float* __restrict__ xq, const float* __restrict__ xk,
    const float* __restrict__ w1, const float* __restrict__ b1,
    const float* __restrict__ v1, const float* __restrict__ bv1,
    float* __restrict__ aW, float* __restrict__ aV,
    float* __restrict__ cW, float* __restrict__ cV,
    int BN, int BK) {
  __shared__ float sw1[CPWc * CPWc];
  __shared__ float sv1[CPWc * COc];
  __shared__ float sb1[CPWc];
  __shared__ float sbv1[COc];
  const int t = threadIdx.x;
  for (int i = t; i < CPWc * CPWc; i += NTH) sw1[i] = w1[i];
  for (int i = t; i < CPWc * COc; i += NTH) sv1[i] = v1[i];
  if (t < CPWc) sb1[t] = b1[t];
  if (t < COc) sbv1[t] = bv1[t];
  __syncthreads();

  const int r = blockIdx.x * NTH + t;
  if (r >= BN + BK) return;
  const bool isQ = (r < BN);
  const int rr = isQ ? r : (r - BN);
  const float* src = isQ ? (xq + (size_t)rr * Cc) : (xk + (size_t)rr * Cc);

  float x[Cc];
#pragma unroll
  for (int i = 0; i < Cc; i += 4) {
    float4 v = *reinterpret_cast<const float4*>(src + i);
    x[i] = v.x; x[i + 1] = v.y; x[i + 2] = v.z; x[i + 3] = v.w;
  }

  if (isQ) {
#pragma unroll
    for (int j = 0; j < CPWc; ++j) {
      float acc = sb1[j];
#pragma unroll
      for (int i = 0; i < Cc; ++i)
        acc += x[i] * (sw1[i * CPWc + j] - sw1[(i + Cc) * CPWc + j]);
      aW[(size_t)rr * CPWc + j] = acc;
    }
#pragma unroll
    for (int j = 0; j < COc; ++j) {
      float acc = sbv1[j];
#pragma unroll
      for (int i = 0; i < Cc; ++i)
        acc += x[i] * (sv1[i * COc + j] - sv1[(i + Cc) * COc + j]);
      aV[(size_t)rr * COc + j] = acc;
    }
  } else {
#pragma unroll
    for (int j = 0; j < CPWc; ++j) {
      float acc = 0.f;
#pragma unroll
      for (int i = 0; i < Cc; ++i) acc += x[i] * sw1[(i + Cc) * CPWc + j];
      cW[(size_t)rr * CPWc + j] = acc;
    }
#pragma unroll
    for (int j = 0; j < COc; ++j) {
      float acc = 0.f;
#pragma unroll
      for (int i = 0; i < Cc; ++i) acc += x[i] * sv1[(i + Cc) * COc + j];
      cV[(size_t)rr * COc + j] = acc;
    }
  }
}

// ---------------------------------------------------------------------------
// Kernel 1b: pack w2 / v2 into per-lane bf16 B-fragments for
// mfma_f32_16x16x32_bf16. Lane l holds B[k = (l>>4)*8 + i][n = l&15],
// i = 0..7. w2: K=32 x N=4 (cols 4..15 zero). v2: K=16 (rows 16..31 zero)
// x N=16.
// ---------------------------------------------------------------------------
__global__ __launch_bounds__(64) void ppa_pack(
    const float* __restrict__ w2, const float* __restrict__ v2,
    ushort* __restrict__ w2f, ushort* __restrict__ v2f) {
  const int l = threadIdx.x;
  const int n = l & 15, g = l >> 4;
#pragma unroll
  for (int i = 0; i < 8; ++i) {
    const int k = g * 8 + i;
    w2f[l * 8 + i] = (n < Hh) ? (ushort)f2bf(w2[k * Hh + n]) : (ushort)0;
    v2f[l * 8 + i] = (k < COc) ? (ushort)f2bf(v2[k * COc + n]) : (ushort)0;
  }
}

// ---------------------------------------------------------------------------
// Kernel 2 (MFMA): one block per (b,n) row, 4 waves, each wave owns a
// 256-k quarter processed as 16 tiles of 16 k's. Per tile:
//   logits tile: A = hw = relu(a + cW)[16x32] bf16 -> mfma 16x16x32 with
//                w2-frag -> D[r] = logits[k=g*4+r][h=lane&15]; p = exp(relu()).
//   val tile:    A = hv = relu(av + cV)[16x16, K-padded] -> mfma with v2-frag
//                -> D[r] = val[k=g*4+r][c=lane&15].
//   p routed logits-lanes -> val-lanes via per-wave LDS bounce (no barrier:
//   same-wave LDS ops are in-order).
// C/D layout col=lane&15,row=(lane>>4)*4+reg is HW-verified (m89); A/B use
// one consistent k-ordering so intra-lane k-permutation errors cancel.
// Softmax is plain exp-sum (logits ReLU'd >= 0; validated r1-r7).
// No launch-bounds cap (r2-r7 law: any cap -> scratch spill).
// ---------------------------------------------------------------------------
__global__ __launch_bounds__(NTH) void ppa_main_mfma(
    const float* __restrict__ aW, const float* __restrict__ aV,
    const float* __restrict__ cW, const float* __restrict__ cV,
    const ushort* __restrict__ w2f, const float* __restrict__ b2,
    const ushort* __restrict__ v2f, const float* __restrict__ bv2,
    float* __restrict__ out, int N, int Nk) {
  __shared__ float pbuf[4][16][Hh];   // per-wave p bounce [wave][k_local][h]
  __shared__ float sro[4][COc];
  __shared__ float srl[4][Hh];

  const int t = threadIdx.x;
  const int lane = t & 63, w = t >> 6;
  const int m = lane & 15;   // A-row within tile; also output col c / head h
  const int g = lane >> 4;   // k-octet group for A/B fragments
  const int row = blockIdx.x;
  const int b = row / N;

  // Loop-invariant per-lane data (registers, loaded once).
  float a_reg[8];
  {
    const float* aRow = aW + (size_t)row * CPWc + g * 8;
#pragma unroll
    for (int i = 0; i < 8; i += 4) {
      F4 v; v.v = *reinterpret_cast<const float4*>(aRow + i);
      a_reg[i] = v.f[0]; a_reg[i + 1] = v.f[1];
      a_reg[i + 2] = v.f[2]; a_reg[i + 3] = v.f[3];
    }
  }
  float av_reg[8];
  {
    const int gg = (g < 2) ? g : 0;  // g>=2 lanes zero their frag; avoid OOB
    const float* avRow = aV + (size_t)row * COc + gg * 8;
#pragma unroll
    for (int i = 0; i < 8; i += 4) {
      F4 v; v.v = *reinterpret_cast<const float4*>(avRow + i);
      av_reg[i] = v.f[0]; av_reg[i + 1] = v.f[1];
      av_reg[i + 2] = v.f[2]; av_reg[i + 3] = v.f[3];
    }
  }
  const bf16x8 wfrag = *reinterpret_cast<const bf16x8*>(w2f + lane * 8);
  const bf16x8 vfrag = *reinterpret_cast<const bf16x8*>(v2f + lane * 8);
  const float b2h = b2[m < Hh ? m : (Hh - 1)];
  const float bv2c = bv2[m];
  const f32x4v zc = {0.f, 0.f, 0.f, 0.f};

  float o_acc = 0.f, l_acc = 0.f;

  const float* cWb = cW + (size_t)b * Nk * CPWc;
  const float* cVb = cV + (size_t)b * Nk * COc;

  const int kPerWave = Nk / 4;        // 256
  const int base0 = w * kPerWave;

#pragma unroll 2
  for (int s = 0; s < kPerWave / 16; ++s) {
    const int km = base0 + s * 16 + m;

    // ---- logits tile: A = hw = relu(a + cW_km)[m][g*8 .. g*8+7]
    const float* pw = cWb + (size_t)km * CPWc + g * 8;
    F4 c0, c1;
    c0.v = *reinterpret_cast<const float4*>(pw);
    c1.v = *reinterpret_cast<const float4*>(pw + 4);
    const bf16x8 afW = {
      f2bf(fmaxf(a_reg[0] + c0.f[0], 0.f)),
      f2bf(fmaxf(a_reg[1] + c0.f[1], 0.f)),
      f2bf(fmaxf(a_reg[2] + c0.f[2], 0.f)),
      f2bf(fmaxf(a_reg[3] + c0.f[3], 0.f)),
      f2bf(fmaxf(a_reg[4] + c1.f[0], 0.f)),
      f2bf(fmaxf(a_reg[5] + c1.f[1], 0.f)),
      f2bf(fmaxf(a_reg[6] + c1.f[2], 0.f)),
      f2bf(fmaxf(a_reg[7] + c1.f[3], 0.f)),
    };
    const f32x4v lgD =
        __builtin_amdgcn_mfma_f32_16x16x32_bf16(afW, wfrag, zc, 0, 0, 0);

    // p = exp(relu(logit + b2)); lane holds rows k_local = g*4 + r, col h=m.
    const float p0 = __expf(fmaxf(lgD[0] + b2h, 0.f));
    const float p1 = __expf(fmaxf(lgD[1] + b2h, 0.f));
    const float p2 = __expf(fmaxf(lgD[2] + b2h, 0.f));
    const float p3 = __expf(fmaxf(lgD[3] + b2h, 0.f));
    if (m < Hh) {
      pbuf[w][g * 4 + 0][m] = p0;
      pbuf[w][g * 4 + 1][m] = p1;
      pbuf[w][g * 4 + 2][m] = p2;
      pbuf[w][g * 4 + 3][m] = p3;
      l_acc += (p0 + p1) + (p2 + p3);
    }

    // ---- val tile: A = hv = relu(av + cV_km)[m][j], K padded 16->32.
    bf16x8 afV = {0, 0, 0, 0, 0, 0, 0, 0};
    if (g < 2) {
      const float* pv = cVb + (size_t)km * COc + g * 8;
      F4 d0, d1;
      d0.v = *reinterpret_cast<const float4*>(pv);
      d1.v = *reinterpret_cast<const float4*>(pv + 4);
      afV = (bf16x8){
        f2bf(fmaxf(av_reg[0] + d0.f[0], 0.f)),
        f2bf(fmaxf(av_reg[1] + d0.f[1], 0.f)),
        f2bf(fmaxf(av_reg[2] + d0.f[2], 0.f)),
        f2bf(fmaxf(av_reg[3] + d0.f[3], 0.f)),
        f2bf(fmaxf(av_reg[4] + d1.f[0], 0.f)),
        f2bf(fmaxf(av_reg[5] + d1.f[1], 0.f)),
        f2bf(fmaxf(av_reg[6] + d1.f[2], 0.f)),
        f2bf(fmaxf(av_reg[7] + d1.f[3], 0.f)),
      };
    }
    const f32x4v vD =
        __builtin_amdgcn_mfma_f32_16x16x32_bf16(afV, vfrag, zc, 0, 0, 0);

    // o[c=m] += p[k][h(m)] * relu(val + bv2), k = g*4 + r (same-wave LDS
    // bounce; DS pipe is in-order within a wave).
    const int hh = m >> 2;
    o_acc += pbuf[w][g * 4 + 0][hh] * fmaxf(vD[0] + bv2c, 0.f);
    o_acc += pbuf[w][g * 4 + 1][hh] * fmaxf(vD[1] + bv2c, 0.f);
    o_acc += pbuf[w][g * 4 + 2][hh] * fmaxf(vD[2] + bv2c, 0.f);
    o_acc += pbuf[w][g * 4 + 3][hh] * fmaxf(vD[3] + bv2c, 0.f);
  }

  // ---- reduce over g-groups (lanes m, m+16, m+32, m+48), then over waves.
  o_acc += __shfl_xor(o_acc, 16);
  o_acc += __shfl_xor(o_acc, 32);
  l_acc += __shfl_xor(l_acc, 16);
  l_acc += __shfl_xor(l_acc, 32);
  if (lane < COc) sro[w][m] = o_acc;
  if (lane < Hh) srl[w][m] = l_acc;
  __syncthreads();

  if (t < COc) {
    const float osum = (sro[0][t] + sro[1][t]) + (sro[2][t] + sro[3][t]);
    const int h = t >> 2;
    const float lsum = (srl[0][h] + srl[1][h]) + (srl[2][h] + srl[3][h]);
    out[(size_t)row * COc + t] = osum / lsum;
  }
}

// ---------------------------------------------------------------------------
extern "C" void kernel_launch(void* const* d_in, const int* in_sizes, int n_in,
                              void* d_out, int out_size, void* d_ws, size_t ws_size,
                              hipStream_t stream) {
  const float* xq  = (const float*)d_in[0];
  const float* xk  = (const float*)d_in[1];
  const float* w1  = (const float*)d_in[2];
  const float* b1  = (const float*)d_in[3];
  const float* w2  = (const float*)d_in[4];
  const float* b2  = (const float*)d_in[5];
  const float* v1  = (const float*)d_in[6];
  const float* bv1 = (const float*)d_in[7];
  const float* v2  = (const float*)d_in[8];
  const float* bv2 = (const float*)d_in[9];
  float* out = (float*)d_out;

  const int BN = in_sizes[0] / Cc;  // B*N  = 2048
  const int BK = in_sizes[1] / Cc;  // B*Nk = 2048
  const int B = 2;                  // fixed by setup_inputs
  const int N = BN / B;
  const int Nk = BK / B;

  float* ws = (float*)d_ws;
  float* aW = ws;                          // BN*32
  float* aV = aW + (size_t)BN * CPWc;      // BN*16
  float* cW = aV + (size_t)BN * COc;       // BK*32
  float* cV = cW + (size_t)BK * CPWc;      // BK*16
  ushort* w2f = (ushort*)(cV + (size_t)BK * COc);  // 64*8 ushort
  ushort* v2f = w2f + 64 * 8;                      // 64*8 ushort

  const int totalRows = BN + BK;
  const int pgrid = (totalRows + NTH - 1) / NTH;
  ppa_precompute<<<pgrid, NTH, 0, stream>>>(xq, xk, w1, b1, v1, bv1,
                                            aW, aV, cW, cV, BN, BK);
  ppa_pack<<<1, 64, 0, stream>>>(w2, v2, w2f, v2f);
  ppa_main_mfma<<<BN, NTH, 0, stream>>>(aW, aV, cW, cV, w2f, b2, v2f, bv2,
                                        out, N, Nk);
}

// Round 9
// 54.234 us; speedup vs baseline: 10.7139x; 1.0707x over previous
//
#include <hip/hip_runtime.h>
#include <hip/hip_bf16.h>
#include <math.h>

// Problem constants (fixed by setup_inputs)
static constexpr int Cc   = 16;   // C
static constexpr int COc  = 16;   // CO
static constexpr int Hh   = 4;    // heads
static constexpr int CPWc = 32;   // 2*C
static constexpr int NTH  = 256;  // block size

typedef __attribute__((ext_vector_type(8))) short bf16x8;   // 8 bf16 = 4 VGPR
typedef __attribute__((ext_vector_type(4))) float f32x4v;   // MFMA C/D

union F4 { float4 v; float f[4]; };

__device__ __forceinline__ short f2bf(float x) {
  __hip_bfloat16 h = __float2bfloat16(x);
  return *reinterpret_cast<short*>(&h);
}

// ---------------------------------------------------------------------------
// Kernel 1: per-row first-layer projections (validated r1-r8) + weight
// packing folded in (block nRowBlocks packs w2/v2 into MFMA B-fragments;
// saves a separate launch).
//   Pack layout (mfma_f32_16x16x32_bf16 B): lane l holds
//   B[k=(l>>4)*8+i][n=l&15], i=0..7. w2: K=32 x N=4 (cols>=4 zero).
//   v2: K=16 (rows>=16 zero) x N=16.
// ---------------------------------------------------------------------------
__global__ __launch_bounds__(NTH) void ppa_precompute(
    const float* __restrict__ xq, const float* __restrict__ xk,
    const float* __restrict__ w1, const float* __restrict__ b1,
    const float* __restrict__ v1, const float* __restrict__ bv1,
    const float* __restrict__ w2, const float* __restrict__ v2,
    float* __restrict__ aW, float* __restrict__ aV,
    float* __restrict__ cW, float* __restrict__ cV,
    ushort* __restrict__ w2f, ushort* __restrict__ v2f,
    int BN, int BK, int nRowBlocks) {
  const int t = threadIdx.x;

  if (blockIdx.x == nRowBlocks) {  // packing block
    if (t < 64) {
      const int n = t & 15, g = t >> 4;
#pragma unroll
      for (int i = 0; i < 8; ++i) {
        const int k = g * 8 + i;
        w2f[t * 8 + i] = (n < Hh) ? (ushort)f2bf(w2[k * Hh + n]) : (ushort)0;
        v2f[t * 8 + i] = (k < COc) ? (ushort)f2bf(v2[k * COc + n]) : (ushort)0;
      }
    }
    return;
  }

  __shared__ float sw1[CPWc * CPWc];
  __shared__ float sv1[CPWc * COc];
  __shared__ float sb1[CPWc];
  __shared__ float sbv1[COc];
  for (int i = t; i < CPWc * CPWc; i += NTH) sw1[i] = w1[i];
  for (int i = t; i < CPWc * COc; i += NTH) sv1[i] = v1[i];
  if (t < CPWc) sb1[t] = b1[t];
  if (t < COc) sbv1[t] = bv1[t];
  __syncthreads();

  const int r = blockIdx.x * NTH + t;
  if (r >= BN + BK) return;
  const bool isQ = (r < BN);
  const int rr = isQ ? r : (r - BN);
  const float* src = isQ ? (xq + (size_t)rr * Cc) : (xk + (size_t)rr * Cc);

  float x[Cc];
#pragma unroll
  for (int i = 0; i < Cc; i += 4) {
    float4 v = *reinterpret_cast<const float4*>(src + i);
    x[i] = v.x; x[i + 1] = v.y; x[i + 2] = v.z; x[i + 3] = v.w;
  }

  if (isQ) {
#pragma unroll
    for (int j = 0; j < CPWc; ++j) {
      float acc = sb1[j];
#pragma unroll
      for (int i = 0; i < Cc; ++i)
        acc += x[i] * (sw1[i * CPWc + j] - sw1[(i + Cc) * CPWc + j]);
      aW[(size_t)rr * CPWc + j] = acc;
    }
#pragma unroll
    for (int j = 0; j < COc; ++j) {
      float acc = sbv1[j];
#pragma unroll
      for (int i = 0; i < Cc; ++i)
        acc += x[i] * (sv1[i * COc + j] - sv1[(i + Cc) * COc + j]);
      aV[(size_t)rr * COc + j] = acc;
    }
  } else {
#pragma unroll
    for (int j = 0; j < CPWc; ++j) {
      float acc = 0.f;
#pragma unroll
      for (int i = 0; i < Cc; ++i) acc += x[i] * sw1[(i + Cc) * CPWc + j];
      cW[(size_t)rr * CPWc + j] = acc;
    }
#pragma unroll
    for (int j = 0; j < COc; ++j) {
      float acc = 0.f;
#pragma unroll
      for (int i = 0; i < Cc; ++i) acc += x[i] * sv1[(i + Cc) * COc + j];
      cV[(size_t)rr * COc + j] = acc;
    }
  }
}

// ---------------------------------------------------------------------------
// Kernel 2 (MFMA): one block per (b,n) row, 4 waves, each wave owns a 256-k
// quarter as 16 tiles of 16 k's. Per tile: logits MFMA (16x16x32, w2-frag),
// p = exp(relu(lg + b2)); p routed head-lanes -> all lanes via __shfl
// (source lane (lane&48)|(m>>2): same 16-lane group; replaces the r8 LDS
// write->read bounce, removing its serialization). val MFMA (K-padded
// v2-frag), o += p * relu(val + bv2).
// l-accum post-shuffle on lanes m&3==0: lane (m,g) holds p[k=g*4+r][h=m>>2],
// so over m in {0,4,8,12} x g, each (h, k-quad) is counted exactly once;
// the xor-16/32 reduction then sums over g (m preserved).
// C/D layout col=lane&15,row=(lane>>4)*4+reg (m89-verified); softmax is
// plain exp-sum (logits ReLU'd >= 0; validated r1-r8). No launch-bounds cap
// (r2-r7 law: cap = 256/w -> spill).
// ---------------------------------------------------------------------------
__global__ __launch_bounds__(NTH) void ppa_main_mfma(
    const float* __restrict__ aW, const float* __restrict__ aV,
    const float* __restrict__ cW, const float* __restrict__ cV,
    const ushort* __restrict__ w2f, const float* __restrict__ b2,
    const ushort* __restrict__ v2f, const float* __restrict__ bv2,
    float* __restrict__ out, int N, int Nk) {
  __shared__ float sro[4][COc];
  __shared__ float srl[4][Hh];

  const int t = threadIdx.x;
  const int lane = t & 63, w = t >> 6;
  const int m = lane & 15;   // A-row in tile; output col c; head col h
  const int g = lane >> 4;   // k-octet group
  const int hh = m >> 2;     // head for this output col
  const int psrc = (lane & 48) | hh;  // lane holding p[.][hh] in this g-group
  const int row = blockIdx.x;
  const int b = row / N;

  // Loop-invariant per-lane data.
  float a_reg[8];
  {
    const float* aRow = aW + (size_t)row * CPWc + g * 8;
#pragma unroll
    for (int i = 0; i < 8; i += 4) {
      F4 v; v.v = *reinterpret_cast<const float4*>(aRow + i);
      a_reg[i] = v.f[0]; a_reg[i + 1] = v.f[1];
      a_reg[i + 2] = v.f[2]; a_reg[i + 3] = v.f[3];
    }
  }
  float av_reg[8];
  {
    const int gg = (g < 2) ? g : 0;  // g>=2 lanes zero their frag; avoid OOB
    const float* avRow = aV + (size_t)row * COc + gg * 8;
#pragma unroll
    for (int i = 0; i < 8; i += 4) {
      F4 v; v.v = *reinterpret_cast<const float4*>(avRow + i);
      av_reg[i] = v.f[0]; av_reg[i + 1] = v.f[1];
      av_reg[i + 2] = v.f[2]; av_reg[i + 3] = v.f[3];
    }
  }
  const bf16x8 wfrag = *reinterpret_cast<const bf16x8*>(w2f + lane * 8);
  const bf16x8 vfrag = *reinterpret_cast<const bf16x8*>(v2f + lane * 8);
  const float b2h = b2[m < Hh ? m : (Hh - 1)];
  const float bv2c = bv2[m];
  const f32x4v zc = {0.f, 0.f, 0.f, 0.f};

  float o_acc = 0.f, l_acc = 0.f;

  const float* cWb = cW + (size_t)b * Nk * CPWc;
  const float* cVb = cV + (size_t)b * Nk * COc;

  const int kPerWave = Nk / 4;        // 256
  const int base0 = w * kPerWave;

#pragma unroll 4
  for (int s = 0; s < kPerWave / 16; ++s) {
    const int km = base0 + s * 16 + m;

    // ---- logits tile: A = hw = relu(a + cW_km)[m][g*8 .. g*8+7]
    const float* pw = cWb + (size_t)km * CPWc + g * 8;
    F4 c0, c1;
    c0.v = *reinterpret_cast<const float4*>(pw);
    c1.v = *reinterpret_cast<const float4*>(pw + 4);
    const bf16x8 afW = {
      f2bf(fmaxf(a_reg[0] + c0.f[0], 0.f)),
      f2bf(fmaxf(a_reg[1] + c0.f[1], 0.f)),
      f2bf(fmaxf(a_reg[2] + c0.f[2], 0.f)),
      f2bf(fmaxf(a_reg[3] + c0.f[3], 0.f)),
      f2bf(fmaxf(a_reg[4] + c1.f[0], 0.f)),
      f2bf(fmaxf(a_reg[5] + c1.f[1], 0.f)),
      f2bf(fmaxf(a_reg[6] + c1.f[2], 0.f)),
      f2bf(fmaxf(a_reg[7] + c1.f[3], 0.f)),
    };
    const f32x4v lgD =
        __builtin_amdgcn_mfma_f32_16x16x32_bf16(afW, wfrag, zc, 0, 0, 0);

    // p on head-lanes (col h = m < 4); rows k_local = g*4 + r.
    const float p0 = __expf(fmaxf(lgD[0] + b2h, 0.f));
    const float p1 = __expf(fmaxf(lgD[1] + b2h, 0.f));
    const float p2 = __expf(fmaxf(lgD[2] + b2h, 0.f));
    const float p3 = __expf(fmaxf(lgD[3] + b2h, 0.f));

    // Route p to all lanes of the g-group (was: LDS bounce in r8).
    const float q0 = __shfl(p0, psrc);
    const float q1 = __shfl(p1, psrc);
    const float q2 = __shfl(p2, psrc);
    const float q3 = __shfl(p3, psrc);
    if ((m & 3) == 0) l_acc += (q0 + q1) + (q2 + q3);

    // ---- val tile: A = hv = relu(av + cV_km)[m][j], K padded 16->32.
    bf16x8 afV = {0, 0, 0, 0, 0, 0, 0, 0};
    if (g < 2) {
      const float* pv = cVb + (size_t)km * COc + g * 8;
      F4 d0, d1;
      d0.v = *reinterpret_cast<const float4*>(pv);
      d1.v = *reinterpret_cast<const float4*>(pv + 4);
      afV = (bf16x8){
        f2bf(fmaxf(av_reg[0] + d0.f[0], 0.f)),
        f2bf(fmaxf(av_reg[1] + d0.f[1], 0.f)),
        f2bf(fmaxf(av_reg[2] + d0.f[2], 0.f)),
        f2bf(fmaxf(av_reg[3] + d0.f[3], 0.f)),
        f2bf(fmaxf(av_reg[4] + d1.f[0], 0.f)),
        f2bf(fmaxf(av_reg[5] + d1.f[1], 0.f)),
        f2bf(fmaxf(av_reg[6] + d1.f[2], 0.f)),
        f2bf(fmaxf(av_reg[7] + d1.f[3], 0.f)),
      };
    }
    const f32x4v vD =
        __builtin_amdgcn_mfma_f32_16x16x32_bf16(afV, vfrag, zc, 0, 0, 0);

    o_acc += q0 * fmaxf(vD[0] + bv2c, 0.f);
    o_acc += q1 * fmaxf(vD[1] + bv2c, 0.f);
    o_acc += q2 * fmaxf(vD[2] + bv2c, 0.f);
    o_acc += q3 * fmaxf(vD[3] + bv2c, 0.f);
  }

  // ---- reduce over g-groups (xor 16/32 preserves m), then across waves.
  o_acc += __shfl_xor(o_acc, 16);
  o_acc += __shfl_xor(o_acc, 32);
  l_acc += __shfl_xor(l_acc, 16);
  l_acc += __shfl_xor(l_acc, 32);
  if (lane < COc) sro[w][m] = o_acc;
  if (lane < COc && (lane & 3) == 0) srl[w][lane >> 2] = l_acc;
  __syncthreads();

  if (t < COc) {
    const float osum = (sro[0][t] + sro[1][t]) + (sro[2][t] + sro[3][t]);
    const int h = t >> 2;
    const float lsum = (srl[0][h] + srl[1][h]) + (srl[2][h] + srl[3][h]);
    out[(size_t)row * COc + t] = osum / lsum;
  }
}

// ---------------------------------------------------------------------------
extern "C" void kernel_launch(void* const* d_in, const int* in_sizes, int n_in,
                              void* d_out, int out_size, void* d_ws, size_t ws_size,
                              hipStream_t stream) {
  const float* xq  = (const float*)d_in[0];
  const float* xk  = (const float*)d_in[1];
  const float* w1  = (const float*)d_in[2];
  const float* b1  = (const float*)d_in[3];
  const float* w2  = (const float*)d_in[4];
  const float* b2  = (const float*)d_in[5];
  const float* v1  = (const float*)d_in[6];
  const float* bv1 = (const float*)d_in[7];
  const float* v2  = (const float*)d_in[8];
  const float* bv2 = (const float*)d_in[9];
  float* out = (float*)d_out;

  const int BN = in_sizes[0] / Cc;  // B*N  = 2048
  const int BK = in_sizes[1] / Cc;  // B*Nk = 2048
  const int B = 2;                  // fixed by setup_inputs
  const int N = BN / B;
  const int Nk = BK / B;

  float* ws = (float*)d_ws;
  float* aW = ws;                          // BN*32
  float* aV = aW + (size_t)BN * CPWc;      // BN*16
  float* cW = aV + (size_t)BN * COc;       // BK*32
  float* cV = cW + (size_t)BK * CPWc;      // BK*16
  ushort* w2f = (ushort*)(cV + (size_t)BK * COc);  // 64*8 ushort
  ushort* v2f = w2f + 64 * 8;                      // 64*8 ushort

  const int totalRows = BN + BK;
  const int pgrid = (totalRows + NTH - 1) / NTH;
  ppa_precompute<<<pgrid + 1, NTH, 0, stream>>>(
      xq, xk, w1, b1, v1, bv1, w2, v2,
      aW, aV, cW, cV, w2f, v2f, BN, BK, pgrid);
  ppa_main_mfma<<<BN, NTH, 0, stream>>>(aW, aV, cW, cV, w2f, b2, v2f, bv2,
                                        out, N, Nk);
}